// Round 1
// 1141.072 us; speedup vs baseline: 1.0056x; 1.0056x over previous
//
#include <hip/hip_runtime.h>
#include <hip/hip_bf16.h>
#include <cmath>

// ---- problem constants ----
#define CC 256
#define WSZ 7
#define WWD_ 56
#define NHD 8
#define HDIM 32
#define KCHN 16
#define KSP 28
#define NTOK 49
#define NWIN 2048
#define NBH 16384
#define LL 3136
#define MTOK 100352
#define MLPH 1024
#define SCALE_Q 0.17677669529663689f

typedef float floatx4 __attribute__((ext_vector_type(4)));
typedef __bf16 bf16x8_t __attribute__((ext_vector_type(8)));

__device__ __forceinline__ float gelu_f(float x) {
    return 0.5f * x * (1.0f + erff(x * 0.7071067811865475f));
}

// async global->LDS DMA, 16B per lane; LDS dest must be wave-uniform base,
// HW writes base + lane*16 (guide §5 / m97 / m151).
__device__ __forceinline__ void lds_dma16(const void* g, void* l) {
    __builtin_amdgcn_global_load_lds((__attribute__((address_space(1))) void*)(void*)g,
                                     (__attribute__((address_space(3))) void*)l, 16, 0, 0);
}

// ---------------- LN row stats ----------------
__global__ __launch_bounds__(64) void ln_stats_k(const float* __restrict__ x,
                                                 float* __restrict__ mu,
                                                 float* __restrict__ rs) {
    int row = blockIdx.x;
    int lane = threadIdx.x;
    float4 v = reinterpret_cast<const float4*>(x + (size_t)row * CC)[lane];
    float s = v.x + v.y + v.z + v.w;
    float s2 = v.x * v.x + v.y * v.y + v.z * v.z + v.w * v.w;
#pragma unroll
    for (int off = 32; off > 0; off >>= 1) {
        s += __shfl_down(s, off);
        s2 += __shfl_down(s2, off);
    }
    if (lane == 0) {
        float m = s * (1.0f / CC);
        float var = s2 * (1.0f / CC) - m * m;
        mu[row] = m;
        rs[row] = rsqrtf(var + 1e-5f);
    }
}

// ---------------- fp32 GEMM for the q path only (top-k selection needs fp32 q) --------
// BM=64, BN=256 (=N, single column block: x read exactly once), BK=16, 8x8 micro-tile.
// B tile staged via global_load_lds (chunk-linear layout); A stays VGPR-staged (LN fused).
struct GP {
    const float* W;
    const float* bias;
    float* C;
    int N, K;
    const float* x;
    const float* mu;
    const float* rs;
    const float* g;
    const float* be;
};

__global__ __launch_bounds__(256) void gemm_q_k(GP p) {
    __shared__ __align__(16) float As[16][68];    // [BK][BM+4]
    __shared__ __align__(16) float Bs[16][256];   // [BK][BN] — linear, NO padding (DMA)
    const int bm = blockIdx.x * 64;
    const int t = threadIdx.x;
    const int tx = t & 31;   // 32 col-threads * 8 cols = 256
    const int ty = t >> 5;   // 8 row-threads * 8 rows = 64
    const int w = t >> 6;    // wave id

    // A staging indices: 4 threads per row, 4 consecutive k each
    const int ar = t >> 2;          // row 0..63
    const int ak = (t & 3) * 4;     // k offset 0/4/8/12

    // LN1 + window-partition fused into A load
    const int r = bm + ar;
    int bwi = r / NTOK, n = r - bwi * NTOK;
    int b = bwi >> 6, rem = bwi & 63;
    int hw = rem >> 3, ww = rem & 7;
    int i0 = n / WSZ, j0 = n - i0 * WSZ;
    size_t grow = (size_t)b * LL + (size_t)(hw * WSZ + i0) * WWD_ + (ww * WSZ + j0);
    const float m = p.mu[grow], rsg = p.rs[grow];
    const float* xrow = p.x + grow * CC;

    float acc[8][8] = {};

    for (int k0 = 0; k0 < CC; k0 += 16) {
        {   // stage A (LN fused), transposed to [k][m]
            const int kk = k0 + ak;
            float4 xv = *reinterpret_cast<const float4*>(xrow + kk);
            float4 gv = *reinterpret_cast<const float4*>(p.g + kk);
            float4 bv = *reinterpret_cast<const float4*>(p.be + kk);
            As[ak + 0][ar] = (xv.x - m) * rsg * gv.x + bv.x;
            As[ak + 1][ar] = (xv.y - m) * rsg * gv.y + bv.y;
            As[ak + 2][ar] = (xv.z - m) * rsg * gv.z + bv.z;
            As[ak + 3][ar] = (xv.w - m) * rsg * gv.w + bv.w;
        }
        // stage B via LDS-DMA: tile = 16x256 f32 = 16KB = 1024 chunks of 16B.
        // chunk c -> row c>>6, float4 c&63; LDS byte addr = c*16 (linear in t).
#pragma unroll
        for (int j = 0; j < 4; ++j) {
            const int c = j * 256 + t;
            const float* gp = p.W + (size_t)(k0 + (c >> 6)) * CC + (c & 63) * 4;
            lds_dma16(gp, (char*)&Bs[0][0] + j * 4096 + w * 1024);
        }
        __syncthreads();
#pragma unroll
        for (int kk = 0; kk < 16; ++kk) {
            float a[8], bb[8];
            *(float4*)&a[0] = *(const float4*)&As[kk][ty * 8];
            *(float4*)&a[4] = *(const float4*)&As[kk][ty * 8 + 4];
            *(float4*)&bb[0] = *(const float4*)&Bs[kk][tx * 8];
            *(float4*)&bb[4] = *(const float4*)&Bs[kk][tx * 8 + 4];
#pragma unroll
            for (int i = 0; i < 8; ++i)
#pragma unroll
                for (int j = 0; j < 8; ++j) acc[i][j] = fmaf(a[i], bb[j], acc[i][j]);
        }
        __syncthreads();
    }

    float bj[8];
#pragma unroll
    for (int j = 0; j < 8; ++j) bj[j] = p.bias[tx * 8 + j];
#pragma unroll
    for (int i = 0; i < 8; ++i) {
        const int row = bm + ty * 8 + i;
        float* crow = p.C + (size_t)row * CC + tx * 8;
#pragma unroll
        for (int j = 0; j < 8; ++j) crow[j] = acc[i][j] + bj[j];
    }
}

// ---------------- bf16 MFMA GEMM: A (M x K bf16), B (N x K bf16, pre-transposed) -------
// EPI: 0 = +bias -> bf16 | 1 = +bias, window-reverse, +resid -> f32
//      2 = +bias, gelu -> bf16 | 3 = +bias, +resid in-place -> f32 (rows offset row0)
struct MG {
    const __hip_bfloat16* A;
    const __hip_bfloat16* B;
    const float* bias;
    int N, K;
    float* Cf;
    __hip_bfloat16* Cb;
    const float* resid;
    int row0;
};

template <int EPI>
__global__ __launch_bounds__(256) void mgemm_k(MG p) {
    __shared__ __align__(16) __hip_bfloat16 As[128 * 32];
    __shared__ __align__(16) __hip_bfloat16 Bs[128 * 32];
    const int bm = blockIdx.x * 128;
    const int bn = blockIdx.y * 128;
    const int t = threadIdx.x;
    const int lane = t & 63;
    const int w = t >> 6;
    const int wm = (w & 1) * 64;
    const int wn = (w >> 1) * 64;
    const int fr = lane & 15;
    const int fk = (lane >> 4) * 8;

    // staging: thread covers 16B chunks t and t+256; chunk c -> row c>>2, k-chunk c&3
    // LDS byte addr of chunk c is c*16 (linear in t) -> global_load_lds applies directly.
    const int m0 = t >> 2, m1 = (t + 256) >> 2;
    const int kc = (t & 3) * 8;
    const __hip_bfloat16* a0 = p.A + (size_t)(bm + m0) * p.K + kc;
    const __hip_bfloat16* a1 = p.A + (size_t)(bm + m1) * p.K + kc;
    const __hip_bfloat16* b0 = p.B + (size_t)(bn + m0) * p.K + kc;
    const __hip_bfloat16* b1 = p.B + (size_t)(bn + m1) * p.K + kc;

    floatx4 acc[4][4] = {};

    for (int k0 = 0; k0 < p.K; k0 += 32) {
        lds_dma16(a0 + k0, &As[w * 512]);
        lds_dma16(a1 + k0, &As[2048 + w * 512]);
        lds_dma16(b0 + k0, &Bs[w * 512]);
        lds_dma16(b1 + k0, &Bs[2048 + w * 512]);
        __syncthreads();
        bf16x8_t af[4], bf[4];
#pragma unroll
        for (int i = 0; i < 4; ++i)
            af[i] = *(const bf16x8_t*)&As[(wm + i * 16 + fr) * 32 + fk];
#pragma unroll
        for (int j = 0; j < 4; ++j)
            bf[j] = *(const bf16x8_t*)&Bs[(wn + j * 16 + fr) * 32 + fk];
#pragma unroll
        for (int i = 0; i < 4; ++i)
#pragma unroll
            for (int j = 0; j < 4; ++j)
                acc[i][j] = __builtin_amdgcn_mfma_f32_16x16x32_bf16(af[i], bf[j], acc[i][j], 0, 0, 0);
        __syncthreads();
    }

    // epilogue: C/D layout col = lane&15, row = (lane>>4)*4 + reg  [m89-verified]
    float bj[4];
#pragma unroll
    for (int j = 0; j < 4; ++j) bj[j] = p.bias[bn + wn + j * 16 + fr];
#pragma unroll
    for (int i = 0; i < 4; ++i) {
#pragma unroll
        for (int r = 0; r < 4; ++r) {
            const int m = bm + wm + i * 16 + (lane >> 4) * 4 + r;
#pragma unroll
            for (int j = 0; j < 4; ++j) {
                const int n = bn + wn + j * 16 + fr;
                float v = acc[i][j][r] + bj[j];
                if constexpr (EPI == 0) {
                    p.Cb[(size_t)m * p.N + n] = __float2bfloat16(v);
                } else if constexpr (EPI == 1) {
                    int bwi = m / NTOK, nn = m - bwi * NTOK;
                    int b = bwi >> 6, rem = bwi & 63;
                    int hw = rem >> 3, wwp = rem & 7;
                    int ii = nn / WSZ, jj = nn - ii * WSZ;
                    size_t oidx = ((size_t)b * LL + (size_t)(hw * WSZ + ii) * WWD_ + (wwp * WSZ + jj)) * CC + n;
                    p.Cf[oidx] = v + p.resid[oidx];
                } else if constexpr (EPI == 2) {
                    p.Cb[(size_t)m * p.N + n] = __float2bfloat16(gelu_f(v));
                } else {
                    size_t gr = (size_t)(m + p.row0);
                    p.Cf[gr * p.N + n] = v + p.resid[gr * p.N + n];
                }
            }
        }
    }
}

// ---------------- weight transpose + bf16 convert: W (K x N f32) -> Wt (N x K bf16) ----
__global__ __launch_bounds__(256) void wt_k(const float* __restrict__ W,
                                            __hip_bfloat16* __restrict__ Wt, int K, int N) {
    int g = blockIdx.x * 256 + threadIdx.x;
    if (g >= K * N) return;
    int n = g / K, kk = g - n * K;
    Wt[g] = __float2bfloat16(W[(size_t)kk * N + n]);
}

// ---------------- top-k (channel 16/32, spatial 28/49) ----------------
__global__ __launch_bounds__(64) void topk_k(const float* __restrict__ q,
                                             const float* __restrict__ wch,
                                             const float* __restrict__ bch,
                                             short* __restrict__ cidx,
                                             short* __restrict__ sidx) {
    int bnh = blockIdx.x;
    int bwi = bnh >> 3, h = bnh & 7;
    int lane = threadIdx.x;
    __shared__ float tile[NTOK][HDIM + 1];
    __shared__ float feat[2 * HDIM];
    __shared__ float score[HDIM];
    __shared__ float rowm[NTOK];
    const float* qbase = q + ((size_t)bwi * NTOK) * CC + h * HDIM;
    for (int idx = lane; idx < NTOK * HDIM; idx += 64) {
        int n = idx >> 5, d = idx & 31;
        tile[n][d] = qbase[(size_t)n * CC + d];
    }
    __syncthreads();
    if (lane < HDIM) {
        float s = 0.f, mx = -INFINITY;
        for (int n = 0; n < NTOK; ++n) {
            float v = tile[n][lane];
            s += v;
            mx = fmaxf(mx, v);
        }
        feat[lane] = s * (1.0f / NTOK);
        feat[HDIM + lane] = mx;
    }
    if (lane < NTOK) {
        float s = 0.f;
        for (int d = 0; d < HDIM; ++d) s += tile[lane][d];
        rowm[lane] = s;
    }
    __syncthreads();
    if (lane < HDIM) {
        float s = bch[lane];
        for (int j = 0; j < 2 * HDIM; ++j) s += feat[j] * wch[j * HDIM + lane];
        score[lane] = gelu_f(s);   // softmax is monotonic: skip for top-k
    }
    __syncthreads();
    {
        bool sel = false;
        if (lane < HDIM) {
            float sv = score[lane];
            int rank = 0;
            for (int j = 0; j < HDIM; ++j) {
                float oj = score[j];
                rank += (oj > sv) || (oj == sv && j < lane);
            }
            sel = rank < KCHN;
        }
        unsigned long long m = __ballot(sel);
        if (sel) {
            int pos = __popcll(m & ((1ull << lane) - 1ull));
            cidx[(size_t)bnh * KCHN + pos] = (short)lane;
        }
    }
    {
        bool sel = false;
        if (lane < NTOK) {
            float sv = rowm[lane];
            int rank = 0;
            for (int j = 0; j < NTOK; ++j) {
                float oj = rowm[j];
                rank += (oj > sv) || (oj == sv && j < lane);
            }
            sel = rank < KSP;
        }
        unsigned long long m = __ballot(sel);
        if (sel) {
            int pos = __popcll(m & ((1ull << lane) - 1ull));
            sidx[(size_t)bnh * KSP + pos] = (short)lane;
        }
    }
}

// ---------------- gathers -> bf16 GEMM inputs ----------------
__global__ __launch_bounds__(256) void gather_ch_k(const float* __restrict__ q,
                                                   const short* __restrict__ cidx,
                                                   __hip_bfloat16* __restrict__ ak) {
    int g = blockIdx.x * 256 + threadIdx.x;   // MTOK*128 elements
    int r = g >> 7, kk = g & 127;
    int bwi = r / NTOK;
    int hp = kk >> 4, c = kk & 15;
    int ci = cidx[((size_t)(bwi * NHD + hp)) * KCHN + c];
    ak[g] = __float2bfloat16(q[(size_t)r * CC + hp * HDIM + ci]);
}

__global__ __launch_bounds__(256) void gather_sp_k(const float* __restrict__ q,
                                                   const short* __restrict__ sidx,
                                                   __hip_bfloat16* __restrict__ av) {
    int g = blockIdx.x * 256 + threadIdx.x;   // NWIN*KSP*256 elements
    int rr = g >> 8, c = g & 255;
    int bwi = rr / KSP, s = rr - bwi * KSP;
    int tok = sidx[((size_t)(bwi * NHD + (c >> 5))) * KSP + s];
    av[g] = __float2bfloat16(q[((size_t)(bwi * NTOK + tok)) * CC + c]);
}

// ---------------- attention (one wave per head-window) ----------------
__global__ __launch_bounds__(64) void attn_k(const float* __restrict__ q,
                                             const __hip_bfloat16* __restrict__ kb,
                                             const __hip_bfloat16* __restrict__ vb,
                                             const short* __restrict__ cidx,
                                             const short* __restrict__ sidx,
                                             const float* __restrict__ rpb,
                                             __hip_bfloat16* __restrict__ ob) {
    int bnh = blockIdx.x;
    int bwi = bnh >> 3, h = bnh & 7;
    int lane = threadIdx.x;
    __shared__ float kh_s[NTOK][KCHN + 1];
    __shared__ float qs_s[KSP][KCHN];
    __shared__ float v_s[KSP][HDIM];
    __shared__ int sidx_s[KSP];
    __shared__ int cidx_s[KCHN];
    if (lane < KSP) sidx_s[lane] = sidx[(size_t)bnh * KSP + lane];
    if (lane < KCHN) cidx_s[lane] = cidx[(size_t)bnh * KCHN + lane];
    for (int idx = lane; idx < NTOK * KCHN; idx += 64) {
        int n = idx >> 4, c = idx & 15;
        kh_s[n][c] = __bfloat162float(kb[((size_t)bwi * NTOK + n) * (NHD * KCHN) + h * KCHN + c]);
    }
    for (int idx = lane; idx < KSP * HDIM; idx += 64) {
        int s = idx >> 5, d = idx & 31;
        v_s[s][d] = __bfloat162float(vb[((size_t)bwi * KSP + s) * CC + h * HDIM + d]);
    }
    __syncthreads();
    for (int idx = lane; idx < KSP * KCHN; idx += 64) {
        int s = idx >> 4, c = idx & 15;
        qs_s[s][c] = q[((size_t)bwi * NTOK + sidx_s[s]) * CC + h * HDIM + cidx_s[c]] * SCALE_Q;
    }
    __syncthreads();
    if (lane < NTOK) {
        int i1 = lane / WSZ, j1 = lane - i1 * WSZ;
        float a[KSP];
        float msum = 0.f;
#pragma unroll
        for (int s = 0; s < KSP; ++s) {
            float dot = 0.f;
#pragma unroll
            for (int c = 0; c < KCHN; ++c) dot += kh_s[lane][c] * qs_s[s][c];
            int m = sidx_s[s];
            int i2 = m / WSZ, j2 = m - i2 * WSZ;
            float bias = rpb[(size_t)((i1 - i2 + 6) * 13 + (j1 - j2 + 6)) * NHD + h];
            a[s] = dot + bias;
            msum += a[s];
        }
        float gate = 1.0f / (1.0f + expf(-msum * (1.0f / KSP)));
        float mx = -INFINITY;
#pragma unroll
        for (int s = 0; s < KSP; ++s) mx = fmaxf(mx, a[s]);
        float sum = 0.f;
#pragma unroll
        for (int s = 0; s < KSP; ++s) {
            a[s] = expf(a[s] - mx);
            sum += a[s];
        }
        float inv = gate / sum;
        __hip_bfloat16* orow = ob + ((size_t)bwi * NTOK + lane) * CC + h * HDIM;
#pragma unroll
        for (int d = 0; d < HDIM; ++d) {
            float od = 0.f;
#pragma unroll
            for (int s = 0; s < KSP; ++s) od += a[s] * v_s[s][d];
            orow[d] = __float2bfloat16(od * inv);
        }
    }
}

// ---------------- LN2 fused normalize -> bf16 ----------------
__global__ __launch_bounds__(64) void ln2_k(const float* __restrict__ x2,
                                            const float* __restrict__ g,
                                            const float* __restrict__ b,
                                            __hip_bfloat16* __restrict__ a2) {
    int row = blockIdx.x;
    int lane = threadIdx.x;
    float4 v = reinterpret_cast<const float4*>(x2 + (size_t)row * CC)[lane];
    float s = v.x + v.y + v.z + v.w;
    float s2 = v.x * v.x + v.y * v.y + v.z * v.z + v.w * v.w;
#pragma unroll
    for (int off = 1; off < 64; off <<= 1) {
        s += __shfl_xor(s, off);
        s2 += __shfl_xor(s2, off);
    }
    float m = s * (1.0f / CC);
    float rsg = rsqrtf(s2 * (1.0f / CC) - m * m + 1e-5f);
    float4 gv = reinterpret_cast<const float4*>(g)[lane];
    float4 bv = reinterpret_cast<const float4*>(b)[lane];
    __hip_bfloat16* orow = a2 + (size_t)row * CC + lane * 4;
    orow[0] = __float2bfloat16((v.x - m) * rsg * gv.x + bv.x);
    orow[1] = __float2bfloat16((v.y - m) * rsg * gv.y + bv.y);
    orow[2] = __float2bfloat16((v.z - m) * rsg * gv.z + bv.z);
    orow[3] = __float2bfloat16((v.w - m) * rsg * gv.w + bv.w);
}

// ---------------- driver ----------------
extern "C" void kernel_launch(void* const* d_in, const int* in_sizes, int n_in,
                              void* d_out, int out_size, void* d_ws, size_t ws_size,
                              hipStream_t stream) {
    const float* x   = (const float*)d_in[0];
    const float* n1g = (const float*)d_in[1];
    const float* n1b = (const float*)d_in[2];
    const float* wq  = (const float*)d_in[3];
    const float* bq  = (const float*)d_in[4];
    const float* wk  = (const float*)d_in[5];
    const float* bk  = (const float*)d_in[6];
    const float* wv  = (const float*)d_in[7];
    const float* bv  = (const float*)d_in[8];
    const float* wpj = (const float*)d_in[9];
    const float* bpj = (const float*)d_in[10];
    const float* wch = (const float*)d_in[11];
    const float* bch = (const float*)d_in[12];
    const float* rpb = (const float*)d_in[13];
    const float* n2g = (const float*)d_in[14];
    const float* n2b = (const float*)d_in[15];
    const float* w1  = (const float*)d_in[16];
    const float* b1  = (const float*)d_in[17];
    const float* w2  = (const float*)d_in[18];
    const float* b2  = (const float*)d_in[19];
    float* out = (float*)d_out;

    // ---- workspace layout (216,449,024 B <= known-good 217,350,144 B) ----
    char* wsb = (char*)d_ws;
    float* qb            = (float*)wsb;                              // 102,760,448 (f32 q)
    __hip_bfloat16* g1   = (__hip_bfloat16*)(wsb + 102760448);       //  25,690,112 (a_k)
    __hip_bfloat16* g2   = (__hip_bfloat16*)(wsb + 128450560);       //  29,360,128 (a_v)
    __hip_bfloat16* ob   = g1;                                       //  51,380,224 (o, overlays g1+g2)
    __hip_bfloat16* kb   = (__hip_bfloat16*)(wsb + 157810688);       //  25,690,112
    __hip_bfloat16* vb   = (__hip_bfloat16*)(wsb + 183500800);       //  29,360,128
    float* mu1           = (float*)(wsb + 212860928);
    float* rs1           = mu1 + MTOK;
    short* cidx          = (short*)(wsb + 213663744);
    short* sidx          = (short*)(wsb + 214188032);
    __hip_bfloat16* wkt  = (__hip_bfloat16*)(wsb + 215105536);
    __hip_bfloat16* wvt  = (__hip_bfloat16*)(wsb + 215138304);
    __hip_bfloat16* wpt  = (__hip_bfloat16*)(wsb + 215269376);
    __hip_bfloat16* w1t  = (__hip_bfloat16*)(wsb + 215400448);
    __hip_bfloat16* w2t  = (__hip_bfloat16*)(wsb + 215924736);
    __hip_bfloat16* a2   = (__hip_bfloat16*)qb;                      // overlays dead qb
    __hip_bfloat16* hb   = (__hip_bfloat16*)(wsb + 51380224);        // overlays qb 2nd half
    if (ws_size < 216449024ULL) return;

    // weight transposes (independent, cheap)
    wt_k<<<(128 * 128 + 255) / 256, 256, 0, stream>>>(wk, wkt, 128, 128);
    wt_k<<<(256 * 256 + 255) / 256, 256, 0, stream>>>(wv, wvt, 256, 256);
    wt_k<<<(256 * 256 + 255) / 256, 256, 0, stream>>>(wpj, wpt, 256, 256);
    wt_k<<<(256 * 1024 + 255) / 256, 256, 0, stream>>>(w1, w1t, 256, 1024);
    wt_k<<<(1024 * 256 + 255) / 256, 256, 0, stream>>>(w2, w2t, 1024, 256);

    ln_stats_k<<<MTOK, 64, 0, stream>>>(x, mu1, rs1);

    // q (fp32 — protects top-k index selection)
    GP p{};
    p.W = wq; p.bias = bq; p.C = qb; p.N = CC; p.K = CC;
    p.x = x; p.mu = mu1; p.rs = rs1; p.g = n1g; p.be = n1b;
    gemm_q_k<<<dim3(MTOK / 64), 256, 0, stream>>>(p);

    topk_k<<<NBH, 64, 0, stream>>>(qb, wch, bch, cidx, sidx);

    gather_ch_k<<<MTOK * 128 / 256, 256, 0, stream>>>(qb, cidx, g1);
    MG m{};
    m.A = g1; m.B = wkt; m.bias = bk; m.N = 128; m.K = 128; m.Cb = kb;
    mgemm_k<0><<<dim3(MTOK / 128, 1), 256, 0, stream>>>(m);

    gather_sp_k<<<NWIN * KSP * 256 / 256, 256, 0, stream>>>(qb, sidx, g2);
    m = MG{};
    m.A = g2; m.B = wvt; m.bias = bv; m.N = CC; m.K = CC; m.Cb = vb;
    mgemm_k<0><<<dim3(NWIN * KSP / 128, 2), 256, 0, stream>>>(m);

    attn_k<<<NBH, 64, 0, stream>>>(qb, kb, vb, cidx, sidx, rpb, ob);

    // out = window_reverse(o @ wproj + bproj) + x
    m = MG{};
    m.A = ob; m.B = wpt; m.bias = bpj; m.N = CC; m.K = CC; m.Cf = out; m.resid = x;
    mgemm_k<1><<<dim3(MTOK / 128, 2), 256, 0, stream>>>(m);

    ln2_k<<<MTOK, 64, 0, stream>>>(out, n2g, n2b, a2);

    const int CHUNK = MTOK / 4;
    for (int c = 0; c < 4; ++c) {
        int start = c * CHUNK;
        m = MG{};
        m.A = a2 + (size_t)start * CC; m.B = w1t; m.bias = b1;
        m.N = MLPH; m.K = CC; m.Cb = hb;
        mgemm_k<2><<<dim3(CHUNK / 128, MLPH / 128), 256, 0, stream>>>(m);

        m = MG{};
        m.A = hb; m.B = w2t; m.bias = b2; m.N = CC; m.K = MLPH;
        m.Cf = out; m.resid = out; m.row0 = start;
        mgemm_k<3><<<dim3(CHUNK / 128, CC / 128), 256, 0, stream>>>(m);
    }
}

// Round 2
// 1138.373 us; speedup vs baseline: 1.0080x; 1.0024x over previous
//
#include <hip/hip_runtime.h>
#include <hip/hip_bf16.h>
#include <cmath>

// ---- problem constants ----
#define CC 256
#define WSZ 7
#define WWD_ 56
#define NHD 8
#define HDIM 32
#define KCHN 16
#define KSP 28
#define NTOK 49
#define NWIN 2048
#define NBH 16384
#define LL 3136
#define MTOK 100352
#define MLPH 1024
#define SCALE_Q 0.17677669529663689f

typedef float floatx4 __attribute__((ext_vector_type(4)));
typedef __bf16 bf16x8_t __attribute__((ext_vector_type(8)));

__device__ __forceinline__ float gelu_f(float x) {
    return 0.5f * x * (1.0f + erff(x * 0.7071067811865475f));
}

// async global->LDS DMA, 16B per lane; LDS dest must be wave-uniform base,
// HW writes base + lane*16 (guide §5 / m97 / m151).
__device__ __forceinline__ void lds_dma16(const void* g, void* l) {
    __builtin_amdgcn_global_load_lds((__attribute__((address_space(1))) void*)(void*)g,
                                     (__attribute__((address_space(3))) void*)l, 16, 0, 0);
}

// ---------------- LN row stats ----------------
__global__ __launch_bounds__(64) void ln_stats_k(const float* __restrict__ x,
                                                 float* __restrict__ mu,
                                                 float* __restrict__ rs) {
    int row = blockIdx.x;
    int lane = threadIdx.x;
    float4 v = reinterpret_cast<const float4*>(x + (size_t)row * CC)[lane];
    float s = v.x + v.y + v.z + v.w;
    float s2 = v.x * v.x + v.y * v.y + v.z * v.z + v.w * v.w;
#pragma unroll
    for (int off = 32; off > 0; off >>= 1) {
        s += __shfl_down(s, off);
        s2 += __shfl_down(s2, off);
    }
    if (lane == 0) {
        float m = s * (1.0f / CC);
        float var = s2 * (1.0f / CC) - m * m;
        mu[row] = m;
        rs[row] = rsqrtf(var + 1e-5f);
    }
}

// ---------------- fp32 GEMM for the q path only (top-k selection needs fp32 q) --------
// BM=64, BN=256 (=N, x read once), BK=16, 8x8 micro-tile.
// 2-deep pipeline: DMA Bs[next] + global A loads issued BEFORE compute of cur tile,
// As written after compute, single barrier per k-step (catalog T3-minimum).
// B columns per thread split {tx*4, 128+tx*4}: ds_read_b128 across 32 lanes = 512B
// contiguous -> no bank conflicts (fixes round-1's 8-way at tx*8).
struct GP {
    const float* W;
    const float* bias;
    float* C;
    int N, K;
    const float* x;
    const float* mu;
    const float* rs;
    const float* g;
    const float* be;
};

__global__ __launch_bounds__(256) void gemm_q_k(GP p) {
    __shared__ __align__(16) float As[2][16][64];    // 8192 B
    __shared__ __align__(16) float Bs[2][16][256];   // 32768 B — linear (DMA), no pad
    const int bm = blockIdx.x * 64;
    const int t = threadIdx.x;
    const int tx = t & 31;   // 32 col-threads
    const int ty = t >> 5;   // 8 row-threads * 8 rows = 64
    const int w = t >> 6;    // wave id

    // A staging indices: 4 threads per row, 4 consecutive k each
    const int ar = t >> 2;          // row 0..63
    const int ak = (t & 3) * 4;     // k offset 0/4/8/12

    // LN1 + window-partition fused into A load
    const int r = bm + ar;
    int bwi = r / NTOK, n = r - bwi * NTOK;
    int b = bwi >> 6, rem = bwi & 63;
    int hw = rem >> 3, ww = rem & 7;
    int i0 = n / WSZ, j0 = n - i0 * WSZ;
    size_t grow = (size_t)b * LL + (size_t)(hw * WSZ + i0) * WWD_ + (ww * WSZ + j0);
    const float m = p.mu[grow], rsg = p.rs[grow];
    const float* xrow = p.x + grow * CC + ak;
    const float* gl = p.g + ak;
    const float* bl = p.be + ak;

    float acc[8][8] = {};

    auto dma_B = [&](int buf, int k0) {
#pragma unroll
        for (int j = 0; j < 4; ++j) {
            const int c = j * 256 + t;   // chunk id; LDS byte = c*16 (linear in t)
            const float* gp = p.W + (size_t)(k0 + (c >> 6)) * CC + (c & 63) * 4;
            lds_dma16(gp, (char*)&Bs[buf][0][0] + j * 4096 + w * 1024);
        }
    };
    auto write_A = [&](int buf, float4 xv, float4 gv, float4 bv) {
        As[buf][ak + 0][ar] = (xv.x - m) * rsg * gv.x + bv.x;
        As[buf][ak + 1][ar] = (xv.y - m) * rsg * gv.y + bv.y;
        As[buf][ak + 2][ar] = (xv.z - m) * rsg * gv.z + bv.z;
        As[buf][ak + 3][ar] = (xv.w - m) * rsg * gv.w + bv.w;
    };

    // prologue: stage tile 0
    {
        float4 xv = *reinterpret_cast<const float4*>(xrow);
        float4 gv = *reinterpret_cast<const float4*>(gl);
        float4 bv = *reinterpret_cast<const float4*>(bl);
        dma_B(0, 0);
        write_A(0, xv, gv, bv);
    }
    __syncthreads();

#pragma unroll
    for (int it = 0; it < 16; ++it) {
        const int cur = it & 1;
        const int nxt = cur ^ 1;
        float4 xv, gv, bv;
        if (it < 15) {   // issue next tile's loads before compute (latency hidden)
            const int k0 = (it + 1) * 16;
            xv = *reinterpret_cast<const float4*>(xrow + k0);
            gv = *reinterpret_cast<const float4*>(gl + k0);
            bv = *reinterpret_cast<const float4*>(bl + k0);
            dma_B(nxt, k0);
        }
#pragma unroll
        for (int kk = 0; kk < 16; ++kk) {
            float a[8], bb[8];
            *(float4*)&a[0] = *(const float4*)&As[cur][kk][ty * 8];
            *(float4*)&a[4] = *(const float4*)&As[cur][kk][ty * 8 + 4];
            *(float4*)&bb[0] = *(const float4*)&Bs[cur][kk][tx * 4];
            *(float4*)&bb[4] = *(const float4*)&Bs[cur][kk][128 + tx * 4];
#pragma unroll
            for (int i = 0; i < 8; ++i)
#pragma unroll
                for (int j = 0; j < 8; ++j) acc[i][j] = fmaf(a[i], bb[j], acc[i][j]);
        }
        if (it < 15) write_A(nxt, xv, gv, bv);
        __syncthreads();
    }

    // epilogue: cols j<4 -> tx*4+j ; j>=4 -> 128+tx*4+(j-4)
    float bj0[4], bj1[4];
#pragma unroll
    for (int j = 0; j < 4; ++j) {
        bj0[j] = p.bias[tx * 4 + j];
        bj1[j] = p.bias[128 + tx * 4 + j];
    }
#pragma unroll
    for (int i = 0; i < 8; ++i) {
        const int row = bm + ty * 8 + i;
        float* crow = p.C + (size_t)row * CC;
        float4 o0 = {acc[i][0] + bj0[0], acc[i][1] + bj0[1], acc[i][2] + bj0[2], acc[i][3] + bj0[3]};
        float4 o1 = {acc[i][4] + bj1[0], acc[i][5] + bj1[1], acc[i][6] + bj1[2], acc[i][7] + bj1[3]};
        *reinterpret_cast<float4*>(crow + tx * 4) = o0;
        *reinterpret_cast<float4*>(crow + 128 + tx * 4) = o1;
    }
}

// ---------------- bf16 MFMA GEMM: A (M x K bf16), B (N x K bf16, pre-transposed) -------
// EPI: 0 = +bias -> bf16 | 1 = +bias, window-reverse, +resid -> f32
//      2 = +bias, gelu -> bf16 | 3 = +bias, +resid in-place -> f32 (rows offset row0)
struct MG {
    const __hip_bfloat16* A;
    const __hip_bfloat16* B;
    const float* bias;
    int N, K;
    float* Cf;
    __hip_bfloat16* Cb;
    const float* resid;
    int row0;
};

template <int EPI>
__global__ __launch_bounds__(256) void mgemm_k(MG p) {
    __shared__ __align__(16) __hip_bfloat16 As[128 * 32];
    __shared__ __align__(16) __hip_bfloat16 Bs[128 * 32];
    const int bm = blockIdx.x * 128;
    const int bn = blockIdx.y * 128;
    const int t = threadIdx.x;
    const int lane = t & 63;
    const int w = t >> 6;
    const int wm = (w & 1) * 64;
    const int wn = (w >> 1) * 64;
    const int fr = lane & 15;
    const int fk = (lane >> 4) * 8;

    // staging: thread covers 16B chunks t and t+256; chunk c -> row c>>2, k-chunk c&3
    // LDS byte addr of chunk c is c*16 (linear in t) -> global_load_lds applies directly.
    const int m0 = t >> 2, m1 = (t + 256) >> 2;
    const int kc = (t & 3) * 8;
    const __hip_bfloat16* a0 = p.A + (size_t)(bm + m0) * p.K + kc;
    const __hip_bfloat16* a1 = p.A + (size_t)(bm + m1) * p.K + kc;
    const __hip_bfloat16* b0 = p.B + (size_t)(bn + m0) * p.K + kc;
    const __hip_bfloat16* b1 = p.B + (size_t)(bn + m1) * p.K + kc;

    floatx4 acc[4][4] = {};

    for (int k0 = 0; k0 < p.K; k0 += 32) {
        lds_dma16(a0 + k0, &As[w * 512]);
        lds_dma16(a1 + k0, &As[2048 + w * 512]);
        lds_dma16(b0 + k0, &Bs[w * 512]);
        lds_dma16(b1 + k0, &Bs[2048 + w * 512]);
        __syncthreads();
        bf16x8_t af[4], bf[4];
#pragma unroll
        for (int i = 0; i < 4; ++i)
            af[i] = *(const bf16x8_t*)&As[(wm + i * 16 + fr) * 32 + fk];
#pragma unroll
        for (int j = 0; j < 4; ++j)
            bf[j] = *(const bf16x8_t*)&Bs[(wn + j * 16 + fr) * 32 + fk];
#pragma unroll
        for (int i = 0; i < 4; ++i)
#pragma unroll
            for (int j = 0; j < 4; ++j)
                acc[i][j] = __builtin_amdgcn_mfma_f32_16x16x32_bf16(af[i], bf[j], acc[i][j], 0, 0, 0);
        __syncthreads();
    }

    // epilogue: C/D layout col = lane&15, row = (lane>>4)*4 + reg  [m89-verified]
    float bj[4];
#pragma unroll
    for (int j = 0; j < 4; ++j) bj[j] = p.bias[bn + wn + j * 16 + fr];
#pragma unroll
    for (int i = 0; i < 4; ++i) {
#pragma unroll
        for (int r = 0; r < 4; ++r) {
            const int m = bm + wm + i * 16 + (lane >> 4) * 4 + r;
#pragma unroll
            for (int j = 0; j < 4; ++j) {
                const int n = bn + wn + j * 16 + fr;
                float v = acc[i][j][r] + bj[j];
                if constexpr (EPI == 0) {
                    p.Cb[(size_t)m * p.N + n] = __float2bfloat16(v);
                } else if constexpr (EPI == 1) {
                    int bwi = m / NTOK, nn = m - bwi * NTOK;
                    int b = bwi >> 6, rem = bwi & 63;
                    int hw = rem >> 3, wwp = rem & 7;
                    int ii = nn / WSZ, jj = nn - ii * WSZ;
                    size_t oidx = ((size_t)b * LL + (size_t)(hw * WSZ + ii) * WWD_ + (wwp * WSZ + jj)) * CC + n;
                    p.Cf[oidx] = v + p.resid[oidx];
                } else if constexpr (EPI == 2) {
                    p.Cb[(size_t)m * p.N + n] = __float2bfloat16(gelu_f(v));
                } else {
                    size_t gr = (size_t)(m + p.row0);
                    p.Cf[gr * p.N + n] = v + p.resid[gr * p.N + n];
                }
            }
        }
    }
}

// ---------------- weight transpose + bf16 convert: W (K x N f32) -> Wt (N x K bf16) ----
__global__ __launch_bounds__(256) void wt_k(const float* __restrict__ W,
                                            __hip_bfloat16* __restrict__ Wt, int K, int N) {
    int g = blockIdx.x * 256 + threadIdx.x;
    if (g >= K * N) return;
    int n = g / K, kk = g - n * K;
    Wt[g] = __float2bfloat16(W[(size_t)kk * N + n]);
}

// ---------------- top-k (channel 16/32, spatial 28/49) ----------------
__global__ __launch_bounds__(64) void topk_k(const float* __restrict__ q,
                                             const float* __restrict__ wch,
                                             const float* __restrict__ bch,
                                             short* __restrict__ cidx,
                                             short* __restrict__ sidx) {
    int bnh = blockIdx.x;
    int bwi = bnh >> 3, h = bnh & 7;
    int lane = threadIdx.x;
    __shared__ float tile[NTOK][HDIM + 1];
    __shared__ float feat[2 * HDIM];
    __shared__ float score[HDIM];
    __shared__ float rowm[NTOK];
    const float* qbase = q + ((size_t)bwi * NTOK) * CC + h * HDIM;
    for (int idx = lane; idx < NTOK * HDIM; idx += 64) {
        int n = idx >> 5, d = idx & 31;
        tile[n][d] = qbase[(size_t)n * CC + d];
    }
    __syncthreads();
    if (lane < HDIM) {
        float s = 0.f, mx = -INFINITY;
        for (int n = 0; n < NTOK; ++n) {
            float v = tile[n][lane];
            s += v;
            mx = fmaxf(mx, v);
        }
        feat[lane] = s * (1.0f / NTOK);
        feat[HDIM + lane] = mx;
    }
    if (lane < NTOK) {
        float s = 0.f;
        for (int d = 0; d < HDIM; ++d) s += tile[lane][d];
        rowm[lane] = s;
    }
    __syncthreads();
    if (lane < HDIM) {
        float s = bch[lane];
        for (int j = 0; j < 2 * HDIM; ++j) s += feat[j] * wch[j * HDIM + lane];
        score[lane] = gelu_f(s);   // softmax is monotonic: skip for top-k
    }
    __syncthreads();
    {
        bool sel = false;
        if (lane < HDIM) {
            float sv = score[lane];
            int rank = 0;
            for (int j = 0; j < HDIM; ++j) {
                float oj = score[j];
                rank += (oj > sv) || (oj == sv && j < lane);
            }
            sel = rank < KCHN;
        }
        unsigned long long m = __ballot(sel);
        if (sel) {
            int pos = __popcll(m & ((1ull << lane) - 1ull));
            cidx[(size_t)bnh * KCHN + pos] = (short)lane;
        }
    }
    {
        bool sel = false;
        if (lane < NTOK) {
            float sv = rowm[lane];
            int rank = 0;
            for (int j = 0; j < NTOK; ++j) {
                float oj = rowm[j];
                rank += (oj > sv) || (oj == sv && j < lane);
            }
            sel = rank < KSP;
        }
        unsigned long long m = __ballot(sel);
        if (sel) {
            int pos = __popcll(m & ((1ull << lane) - 1ull));
            sidx[(size_t)bnh * KSP + pos] = (short)lane;
        }
    }
}

// ---------------- gathers -> bf16 GEMM inputs ----------------
__global__ __launch_bounds__(256) void gather_ch_k(const float* __restrict__ q,
                                                   const short* __restrict__ cidx,
                                                   __hip_bfloat16* __restrict__ ak) {
    int g = blockIdx.x * 256 + threadIdx.x;   // MTOK*128 elements
    int r = g >> 7, kk = g & 127;
    int bwi = r / NTOK;
    int hp = kk >> 4, c = kk & 15;
    int ci = cidx[((size_t)(bwi * NHD + hp)) * KCHN + c];
    ak[g] = __float2bfloat16(q[(size_t)r * CC + hp * HDIM + ci]);
}

__global__ __launch_bounds__(256) void gather_sp_k(const float* __restrict__ q,
                                                   const short* __restrict__ sidx,
                                                   __hip_bfloat16* __restrict__ av) {
    int g = blockIdx.x * 256 + threadIdx.x;   // NWIN*KSP*256 elements
    int rr = g >> 8, c = g & 255;
    int bwi = rr / KSP, s = rr - bwi * KSP;
    int tok = sidx[((size_t)(bwi * NHD + (c >> 5))) * KSP + s];
    av[g] = __float2bfloat16(q[((size_t)(bwi * NTOK + tok)) * CC + c]);
}

// ---------------- attention (one wave per head-window) ----------------
__global__ __launch_bounds__(64) void attn_k(const float* __restrict__ q,
                                             const __hip_bfloat16* __restrict__ kb,
                                             const __hip_bfloat16* __restrict__ vb,
                                             const short* __restrict__ cidx,
                                             const short* __restrict__ sidx,
                                             const float* __restrict__ rpb,
                                             __hip_bfloat16* __restrict__ ob) {
    int bnh = blockIdx.x;
    int bwi = bnh >> 3, h = bnh & 7;
    int lane = threadIdx.x;
    __shared__ float kh_s[NTOK][KCHN + 1];
    __shared__ float qs_s[KSP][KCHN];
    __shared__ float v_s[KSP][HDIM];
    __shared__ int sidx_s[KSP];
    __shared__ int cidx_s[KCHN];
    if (lane < KSP) sidx_s[lane] = sidx[(size_t)bnh * KSP + lane];
    if (lane < KCHN) cidx_s[lane] = cidx[(size_t)bnh * KCHN + lane];
    for (int idx = lane; idx < NTOK * KCHN; idx += 64) {
        int n = idx >> 4, c = idx & 15;
        kh_s[n][c] = __bfloat162float(kb[((size_t)bwi * NTOK + n) * (NHD * KCHN) + h * KCHN + c]);
    }
    for (int idx = lane; idx < KSP * HDIM; idx += 64) {
        int s = idx >> 5, d = idx & 31;
        v_s[s][d] = __bfloat162float(vb[((size_t)bwi * KSP + s) * CC + h * HDIM + d]);
    }
    __syncthreads();
    for (int idx = lane; idx < KSP * KCHN; idx += 64) {
        int s = idx >> 4, c = idx & 15;
        qs_s[s][c] = q[((size_t)bwi * NTOK + sidx_s[s]) * CC + h * HDIM + cidx_s[c]] * SCALE_Q;
    }
    __syncthreads();
    if (lane < NTOK) {
        int i1 = lane / WSZ, j1 = lane - i1 * WSZ;
        float a[KSP];
        float msum = 0.f;
#pragma unroll
        for (int s = 0; s < KSP; ++s) {
            float dot = 0.f;
#pragma unroll
            for (int c = 0; c < KCHN; ++c) dot += kh_s[lane][c] * qs_s[s][c];
            int m = sidx_s[s];
            int i2 = m / WSZ, j2 = m - i2 * WSZ;
            float bias = rpb[(size_t)((i1 - i2 + 6) * 13 + (j1 - j2 + 6)) * NHD + h];
            a[s] = dot + bias;
            msum += a[s];
        }
        float gate = 1.0f / (1.0f + expf(-msum * (1.0f / KSP)));
        float mx = -INFINITY;
#pragma unroll
        for (int s = 0; s < KSP; ++s) mx = fmaxf(mx, a[s]);
        float sum = 0.f;
#pragma unroll
        for (int s = 0; s < KSP; ++s) {
            a[s] = expf(a[s] - mx);
            sum += a[s];
        }
        float inv = gate / sum;
        __hip_bfloat16* orow = ob + ((size_t)bwi * NTOK + lane) * CC + h * HDIM;
#pragma unroll
        for (int d = 0; d < HDIM; ++d) {
            float od = 0.f;
#pragma unroll
            for (int s = 0; s < KSP; ++s) od += a[s] * v_s[s][d];
            orow[d] = __float2bfloat16(od * inv);
        }
    }
}

// ---------------- LN2 fused normalize -> bf16 ----------------
__global__ __launch_bounds__(64) void ln2_k(const float* __restrict__ x2,
                                            const float* __restrict__ g,
                                            const float* __restrict__ b,
                                            __hip_bfloat16* __restrict__ a2) {
    int row = blockIdx.x;
    int lane = threadIdx.x;
    float4 v = reinterpret_cast<const float4*>(x2 + (size_t)row * CC)[lane];
    float s = v.x + v.y + v.z + v.w;
    float s2 = v.x * v.x + v.y * v.y + v.z * v.z + v.w * v.w;
#pragma unroll
    for (int off = 1; off < 64; off <<= 1) {
        s += __shfl_xor(s, off);
        s2 += __shfl_xor(s2, off);
    }
    float m = s * (1.0f / CC);
    float rsg = rsqrtf(s2 * (1.0f / CC) - m * m + 1e-5f);
    float4 gv = reinterpret_cast<const float4*>(g)[lane];
    float4 bv = reinterpret_cast<const float4*>(b)[lane];
    __hip_bfloat16* orow = a2 + (size_t)row * CC + lane * 4;
    orow[0] = __float2bfloat16((v.x - m) * rsg * gv.x + bv.x);
    orow[1] = __float2bfloat16((v.y - m) * rsg * gv.y + bv.y);
    orow[2] = __float2bfloat16((v.z - m) * rsg * gv.z + bv.z);
    orow[3] = __float2bfloat16((v.w - m) * rsg * gv.w + bv.w);
}

// ---------------- driver ----------------
extern "C" void kernel_launch(void* const* d_in, const int* in_sizes, int n_in,
                              void* d_out, int out_size, void* d_ws, size_t ws_size,
                              hipStream_t stream) {
    const float* x   = (const float*)d_in[0];
    const float* n1g = (const float*)d_in[1];
    const float* n1b = (const float*)d_in[2];
    const float* wq  = (const float*)d_in[3];
    const float* bq  = (const float*)d_in[4];
    const float* wk  = (const float*)d_in[5];
    const float* bk  = (const float*)d_in[6];
    const float* wv  = (const float*)d_in[7];
    const float* bv  = (const float*)d_in[8];
    const float* wpj = (const float*)d_in[9];
    const float* bpj = (const float*)d_in[10];
    const float* wch = (const float*)d_in[11];
    const float* bch = (const float*)d_in[12];
    const float* rpb = (const float*)d_in[13];
    const float* n2g = (const float*)d_in[14];
    const float* n2b = (const float*)d_in[15];
    const float* w1  = (const float*)d_in[16];
    const float* b1  = (const float*)d_in[17];
    const float* w2  = (const float*)d_in[18];
    const float* b2  = (const float*)d_in[19];
    float* out = (float*)d_out;

    // ---- workspace layout (216,449,024 B <= known-good 217,350,144 B) ----
    char* wsb = (char*)d_ws;
    float* qb            = (float*)wsb;                              // 102,760,448 (f32 q)
    __hip_bfloat16* g1   = (__hip_bfloat16*)(wsb + 102760448);       //  25,690,112 (a_k)
    __hip_bfloat16* g2   = (__hip_bfloat16*)(wsb + 128450560);       //  29,360,128 (a_v)
    __hip_bfloat16* ob   = g1;                                       //  51,380,224 (o, overlays g1+g2)
    __hip_bfloat16* kb   = (__hip_bfloat16*)(wsb + 157810688);       //  25,690,112
    __hip_bfloat16* vb   = (__hip_bfloat16*)(wsb + 183500800);       //  29,360,128
    float* mu1           = (float*)(wsb + 212860928);
    float* rs1           = mu1 + MTOK;
    short* cidx          = (short*)(wsb + 213663744);
    short* sidx          = (short*)(wsb + 214188032);
    __hip_bfloat16* wkt  = (__hip_bfloat16*)(wsb + 215105536);
    __hip_bfloat16* wvt  = (__hip_bfloat16*)(wsb + 215138304);
    __hip_bfloat16* wpt  = (__hip_bfloat16*)(wsb + 215269376);
    __hip_bfloat16* w1t  = (__hip_bfloat16*)(wsb + 215400448);
    __hip_bfloat16* w2t  = (__hip_bfloat16*)(wsb + 215924736);
    __hip_bfloat16* a2   = (__hip_bfloat16*)qb;                      // overlays dead qb
    __hip_bfloat16* hb   = (__hip_bfloat16*)(wsb + 51380224);        // overlays qb 2nd half
    if (ws_size < 216449024ULL) return;

    // weight transposes (independent, cheap)
    wt_k<<<(128 * 128 + 255) / 256, 256, 0, stream>>>(wk, wkt, 128, 128);
    wt_k<<<(256 * 256 + 255) / 256, 256, 0, stream>>>(wv, wvt, 256, 256);
    wt_k<<<(256 * 256 + 255) / 256, 256, 0, stream>>>(wpj, wpt, 256, 256);
    wt_k<<<(256 * 1024 + 255) / 256, 256, 0, stream>>>(w1, w1t, 256, 1024);
    wt_k<<<(1024 * 256 + 255) / 256, 256, 0, stream>>>(w2, w2t, 1024, 256);

    ln_stats_k<<<MTOK, 64, 0, stream>>>(x, mu1, rs1);

    // q (fp32 — protects top-k index selection)
    GP p{};
    p.W = wq; p.bias = bq; p.C = qb; p.N = CC; p.K = CC;
    p.x = x; p.mu = mu1; p.rs = rs1; p.g = n1g; p.be = n1b;
    gemm_q_k<<<dim3(MTOK / 64), 256, 0, stream>>>(p);

    topk_k<<<NBH, 64, 0, stream>>>(qb, wch, bch, cidx, sidx);

    gather_ch_k<<<MTOK * 128 / 256, 256, 0, stream>>>(qb, cidx, g1);
    MG m{};
    m.A = g1; m.B = wkt; m.bias = bk; m.N = 128; m.K = 128; m.Cb = kb;
    mgemm_k<0><<<dim3(MTOK / 128, 1), 256, 0, stream>>>(m);

    gather_sp_k<<<NWIN * KSP * 256 / 256, 256, 0, stream>>>(qb, sidx, g2);
    m = MG{};
    m.A = g2; m.B = wvt; m.bias = bv; m.N = CC; m.K = CC; m.Cb = vb;
    mgemm_k<0><<<dim3(NWIN * KSP / 128, 2), 256, 0, stream>>>(m);

    attn_k<<<NBH, 64, 0, stream>>>(qb, kb, vb, cidx, sidx, rpb, ob);

    // out = window_reverse(o @ wproj + bproj) + x
    m = MG{};
    m.A = ob; m.B = wpt; m.bias = bpj; m.N = CC; m.K = CC; m.Cf = out; m.resid = x;
    mgemm_k<1><<<dim3(MTOK / 128, 2), 256, 0, stream>>>(m);

    ln2_k<<<MTOK, 64, 0, stream>>>(out, n2g, n2b, a2);

    const int CHUNK = MTOK / 4;
    for (int c = 0; c < 4; ++c) {
        int start = c * CHUNK;
        m = MG{};
        m.A = a2 + (size_t)start * CC; m.B = w1t; m.bias = b1;
        m.N = MLPH; m.K = CC; m.Cb = hb;
        mgemm_k<2><<<dim3(CHUNK / 128, MLPH / 128), 256, 0, stream>>>(m);

        m = MG{};
        m.A = hb; m.B = w2t; m.bias = b2; m.N = CC; m.K = MLPH;
        m.Cf = out; m.resid = out; m.row0 = start;
        mgemm_k<3><<<dim3(CHUNK / 128, CC / 128), 256, 0, stream>>>(m);
    }
}